// Round 1
// 421.642 us; speedup vs baseline: 1.2018x; 1.2018x over previous
//
#include <hip/hip_runtime.h>
#include <math.h>

#define B_ 16
#define S_ 1024
#define D_ 256
#define F_ 256
#define T_ 8192
#define ROWS (B_ * S_)  // 16384

typedef __attribute__((ext_vector_type(8))) short short8x;
typedef __attribute__((ext_vector_type(4))) float f32x4;

static __device__ __forceinline__ unsigned short f2bf(float f) {
    unsigned u = __float_as_uint(f);
    unsigned r = (u + 0x7FFFu + ((u >> 16) & 1u)) >> 16;  // round-to-nearest-even
    return (unsigned short)r;
}
static __device__ __forceinline__ float bf2f(unsigned short h) {
    return __uint_as_float(((unsigned)h) << 16);
}

// ============================================================
// K0: weight prep.
//   t=0..3: pp1, ep1, pp2, ep2 -> plain bf16 [k][o][c]
//   t=4..5: dp1, dp2 -> split hi/lo bf16 [k][o][c] pairs
// ============================================================
__global__ __launch_bounds__(256) void wprep_kernel(
    const float* __restrict__ pw1, const float* __restrict__ ew1,
    const float* __restrict__ pw2, const float* __restrict__ ew2,
    const float* __restrict__ dw1, const float* __restrict__ dw2,
    unsigned short* __restrict__ wt)
{
    int idx = blockIdx.x * 256 + threadIdx.x;   // 0..393215
    int t = idx >> 16;
    int rem = idx & 65535;
    int o = rem >> 8, c = rem & 255;
    if (t < 4) {
        const float* src = (t == 0) ? pw1 : (t == 1) ? ew1 : (t == 2) ? pw2 : ew2;
        const float* p = src + ((size_t)o * 256 + c) * 3;
        unsigned short* dst = wt + (size_t)t * 196608;
        #pragma unroll
        for (int k = 0; k < 3; ++k)
            dst[((size_t)k * 256 + o) * 256 + c] = f2bf(p[k]);
    } else {
        const float* src = (t == 4) ? dw1 : dw2;
        const float* p = src + ((size_t)o * 256 + c) * 3;
        unsigned short* dh = wt + (size_t)(4 + 2 * (t - 4)) * 196608;
        unsigned short* dl = dh + 196608;
        #pragma unroll
        for (int k = 0; k < 3; ++k) {
            float v = p[k];
            unsigned short hi = f2bf(v);
            size_t off = ((size_t)k * 256 + o) * 256 + c;
            dh[off] = hi;
            dl[off] = f2bf(v - bf2f(hi));
        }
    }
}

// ============================================================
// K1: x' = x + note_pitch @ np_w + np_b  (+ init reduction cells)
// ============================================================
__global__ __launch_bounds__(256) void noteproj_kernel(
    const float* __restrict__ x, const float* __restrict__ note,
    const float* __restrict__ w, const float* __restrict__ bias,
    float* __restrict__ xp, unsigned* __restrict__ red)
{
    if (blockIdx.x == 0 && blockIdx.y == 0 && threadIdx.x == 0) {
        red[0] = 0u;            // max ||xn||
        red[1] = 0x7F7FFFFFu;   // min ||x'||  (FLT_MAX bits)
        red[2] = 0u;            // max ||x'||
    }
    __shared__ float As[16][66];
    __shared__ float Bs[16][68];
    const int tid = threadIdx.x;
    const int m0 = blockIdx.x << 6;
    const int o0 = blockIdx.y << 6;
    const int tc = tid & 15, tr = tid >> 4;
    const int r = tr << 2, oc = tc << 2;
    const int tA = tid >> 2, cg = (tid & 3) << 2;
    const int cB = tid >> 4, oB = (tid & 15) << 2;
    float acc[4][4] = {};

    for (int c0 = 0; c0 < D_; c0 += 16) {
        float4 av = *(const float4*)(note + (size_t)(m0 + tA) * D_ + c0 + cg);
        As[cg + 0][tA] = av.x; As[cg + 1][tA] = av.y;
        As[cg + 2][tA] = av.z; As[cg + 3][tA] = av.w;
        *(float4*)&Bs[cB][oB] = *(const float4*)(w + (size_t)(c0 + cB) * D_ + o0 + oB);
        __syncthreads();
        #pragma unroll
        for (int c = 0; c < 16; ++c) {
            float a[4], bv[4];
            #pragma unroll
            for (int m = 0; m < 4; ++m) a[m] = As[c][r + m];
            #pragma unroll
            for (int j = 0; j < 4; ++j) bv[j] = Bs[c][oc + j];
            #pragma unroll
            for (int i = 0; i < 4; ++i)
                #pragma unroll
                for (int j = 0; j < 4; ++j)
                    acc[i][j] = fmaf(a[i], bv[j], acc[i][j]);
        }
        __syncthreads();
    }
    #pragma unroll
    for (int i = 0; i < 4; ++i) {
        size_t row = (size_t)(m0 + r + i);
        const float* xr = x + row * D_ + o0 + oc;
        float4 v;
        v.x = acc[i][0] + bias[o0 + oc + 0] + xr[0];
        v.y = acc[i][1] + bias[o0 + oc + 1] + xr[1];
        v.z = acc[i][2] + bias[o0 + oc + 2] + xr[2];
        v.w = acc[i][3] + bias[o0 + oc + 3] + xr[3];
        *(float4*)(xp + row * D_ + o0 + oc) = v;
    }
}

// ============================================================
// K2: layernorm + norms + bf16 copies. 1 wave = 1 row.
//     xn is emitted ONLY as a hi/lo bf16 split (for the dp MFMA path).
// ============================================================
__global__ __launch_bounds__(256) void rowstats_kernel(
    const float* __restrict__ xp, const float* __restrict__ g, const float* __restrict__ bb,
    unsigned short* __restrict__ xnh, unsigned short* __restrict__ xnl,
    float* __restrict__ nxn, float* __restrict__ nx,
    unsigned short* __restrict__ xpb)
{
    int row = blockIdx.x * 4 + (threadIdx.x >> 6);
    int lane = threadIdx.x & 63;
    float4 v = ((const float4*)(xp + (size_t)row * D_))[lane];
    // bf16 copy for the pp/ep MFMA paths (consume x')
    ushort4 bv4;
    bv4.x = f2bf(v.x); bv4.y = f2bf(v.y); bv4.z = f2bf(v.z); bv4.w = f2bf(v.w);
    ((ushort4*)xpb)[(size_t)row * 64 + lane] = bv4;

    float s = v.x + v.y + v.z + v.w;
    float sq = v.x * v.x + v.y * v.y + v.z * v.z + v.w * v.w;
    #pragma unroll
    for (int m = 32; m; m >>= 1) { s += __shfl_xor(s, m); sq += __shfl_xor(sq, m); }
    float mean = s * (1.f / 256.f);
    float var = sq * (1.f / 256.f) - mean * mean;
    float rs = rsqrtf(var + 1e-5f);
    float4 gv = ((const float4*)g)[lane];
    float4 bv = ((const float4*)bb)[lane];
    float4 o;
    o.x = gv.x * (v.x - mean) * rs + bv.x;
    o.y = gv.y * (v.y - mean) * rs + bv.y;
    o.z = gv.z * (v.z - mean) * rs + bv.z;
    o.w = gv.w * (v.w - mean) * rs + bv.w;
    // split-bf16 store of xn (hi + lo captures ~16 mantissa bits)
    ushort4 h4, l4;
    h4.x = f2bf(o.x); l4.x = f2bf(o.x - bf2f(h4.x));
    h4.y = f2bf(o.y); l4.y = f2bf(o.y - bf2f(h4.y));
    h4.z = f2bf(o.z); l4.z = f2bf(o.z - bf2f(h4.z));
    h4.w = f2bf(o.w); l4.w = f2bf(o.w - bf2f(h4.w));
    ((ushort4*)xnh)[(size_t)row * 64 + lane] = h4;
    ((ushort4*)xnl)[(size_t)row * 64 + lane] = l4;

    float q = o.x * o.x + o.y * o.y + o.z * o.z + o.w * o.w;
    #pragma unroll
    for (int m = 32; m; m >>= 1) q += __shfl_xor(q, m);
    if (lane == 0) { nxn[row] = sqrtf(q); nx[row] = sqrtf(sq); }
}

// ============================================================
// K3: fast global reduce via uint-monotonic atomics (positive floats)
// ============================================================
__global__ __launch_bounds__(256) void reduce_fast_kernel(
    const float* __restrict__ nxn, const float* __restrict__ nx, unsigned* __restrict__ red)
{
    int tid = threadIdx.x;
    int lane = tid & 63, wave = tid >> 6;
    float mxn = 0.f, mnx = 3.0e38f, mxx = 0.f;
    for (int i = blockIdx.x * 256 + tid; i < ROWS; i += 32 * 256) {
        mxn = fmaxf(mxn, nxn[i]);
        float v = nx[i];
        mnx = fminf(mnx, v);
        mxx = fmaxf(mxx, v);
    }
    #pragma unroll
    for (int m = 32; m; m >>= 1) {
        mxn = fmaxf(mxn, __shfl_xor(mxn, m));
        mnx = fminf(mnx, __shfl_xor(mnx, m));
        mxx = fmaxf(mxx, __shfl_xor(mxx, m));
    }
    __shared__ float a0[4], a1[4], a2[4];
    if (lane == 0) { a0[wave] = mxn; a1[wave] = mnx; a2[wave] = mxx; }
    __syncthreads();
    if (tid == 0) {
        #pragma unroll
        for (int w2 = 1; w2 < 4; ++w2) {
            mxn = fmaxf(mxn, a0[w2]); mnx = fminf(mnx, a1[w2]); mxx = fmaxf(mxx, a2[w2]);
        }
        atomicMax(&red[0], __float_as_uint(mxn));
        atomicMin(&red[1], __float_as_uint(mnx));
        atomicMax(&red[2], __float_as_uint(mxx));
    }
}

// ============================================================
// K4: all-MFMA conv stage (16x16x32 bf16, 3 shifted taps for K=3).
//   z=0: dp path, split-bf16 (3-term: hi*hi + hi*lo + lo*hi) for
//        fp32-like accuracy (durations feed round->cumsum->gather).
//   z=1,2: pp/ep plain bf16 path (unchanged from previous version).
// grid (128, 4, 3), 256 threads.
// ============================================================
struct ConvAll {
    // dp split path
    const unsigned short* dp_in_hi; const unsigned short* dp_in_lo;   // [B*S][256]
    const unsigned short* dp_wt_hi; const unsigned short* dp_wt_lo;   // [3][256][256]
    const float* dp_bias;
    unsigned short* dp_out_hi; unsigned short* dp_out_lo;  // stage1 (bfout=1)
    float* dp_out_f;                                        // stage2 (bfout=0)
    // pp / ep
    const unsigned short* inb[2];
    const unsigned short* wt[2];
    const float* bias[2];
    void* out[2];
    int bfout;                        // 1: bf16 out (stage1), 0: fp32 out (stage2)
};

__global__ __launch_bounds__(256) void convall_kernel(ConvAll cb)
{
    __shared__ __align__(16) char smem[51520];
    const int tid = threadIdx.x;
    const int z = blockIdx.z;
    const int b = blockIdx.x >> 3;
    const int s0 = (blockIdx.x & 7) << 7;
    const int o0 = blockIdx.y << 6;
    const int wave = tid >> 6, lane = tid & 63;
    const int wm = wave << 5;              // 32 output rows per wave
    const int lm = lane & 15, lk8 = (lane >> 4) << 3;
    f32x4 acc[2][4] = {};

    // per-thread staging coords (shared by both paths)
    int ta[3], pa_off[3], sa[3]; bool va[3];
    int kb[3], ob[3], pbo[3];
    #pragma unroll
    for (int rr = 0; rr < 3; ++rr) {
        int slotA = tid + (rr << 8);
        ta[rr] = slotA >> 2; pa_off[rr] = (slotA & 3) << 3;
        sa[rr] = s0 - 1 + ta[rr];
        va[rr] = (slotA < 520) && (sa[rr] >= 0) && (sa[rr] < S_);
        int slotB = tid + (rr << 8);       // 768 slots exactly
        kb[rr] = slotB >> 8;
        int rem = slotB & 255;
        ob[rr] = rem >> 2; pbo[rr] = (rem & 3) << 3;
    }

    if (z == 0) {
        // ---------------- dp split-bf16 path ----------------
        unsigned short* Ah = (unsigned short*)smem;        // [130][40]
        unsigned short* Al = Ah + 5200;                    // [130][40]
        unsigned short* Bh = Al + 5200;                    // [3][64][40]
        unsigned short* Bl = Bh + 7680;                    // [3][64][40]  (total 51520 B)
        const unsigned short* ih = cb.dp_in_hi + (size_t)b * S_ * D_;
        const unsigned short* il = cb.dp_in_lo + (size_t)b * S_ * D_;
        uint4 pah[3], pal[3], pbh[3], pbl[3];
        auto pref = [&](int c0) {
            #pragma unroll
            for (int rr = 0; rr < 3; ++rr) {
                uint4 vh = make_uint4(0u, 0u, 0u, 0u);
                uint4 vl = make_uint4(0u, 0u, 0u, 0u);
                if (va[rr]) {
                    size_t aoff = (size_t)sa[rr] * D_ + c0 + pa_off[rr];
                    vh = *(const uint4*)(const void*)(ih + aoff);
                    vl = *(const uint4*)(const void*)(il + aoff);
                }
                pah[rr] = vh; pal[rr] = vl;
                size_t woff = ((size_t)kb[rr] * 256 + (o0 + ob[rr])) * 256 + c0 + pbo[rr];
                pbh[rr] = *(const uint4*)(const void*)(cb.dp_wt_hi + woff);
                pbl[rr] = *(const uint4*)(const void*)(cb.dp_wt_lo + woff);
            }
        };
        pref(0);
        for (int c0 = 0; c0 < D_; c0 += 32) {
            #pragma unroll
            for (int rr = 0; rr < 3; ++rr) {
                if (tid + (rr << 8) < 520) {
                    *(uint4*)(void*)&Ah[ta[rr] * 40 + pa_off[rr]] = pah[rr];
                    *(uint4*)(void*)&Al[ta[rr] * 40 + pa_off[rr]] = pal[rr];
                }
                *(uint4*)(void*)&Bh[((kb[rr] << 6) + ob[rr]) * 40 + pbo[rr]] = pbh[rr];
                *(uint4*)(void*)&Bl[((kb[rr] << 6) + ob[rr]) * 40 + pbo[rr]] = pbl[rr];
            }
            __syncthreads();
            if (c0 + 32 < D_) pref(c0 + 32);
            #pragma unroll
            for (int k = 0; k < 3; ++k) {
                short8x a0h = *(short8x*)(void*)&Ah[(wm + lm + k) * 40 + lk8];
                short8x a0l = *(short8x*)(void*)&Al[(wm + lm + k) * 40 + lk8];
                short8x a1h = *(short8x*)(void*)&Ah[(wm + 16 + lm + k) * 40 + lk8];
                short8x a1l = *(short8x*)(void*)&Al[(wm + 16 + lm + k) * 40 + lk8];
                #pragma unroll
                for (int nt = 0; nt < 4; ++nt) {
                    int boff = ((k << 6) + (nt << 4) + lm) * 40 + lk8;
                    short8x bh = *(short8x*)(void*)&Bh[boff];
                    short8x bl = *(short8x*)(void*)&Bl[boff];
                    acc[0][nt] = __builtin_amdgcn_mfma_f32_16x16x32_bf16(a0h, bh, acc[0][nt], 0, 0, 0);
                    acc[1][nt] = __builtin_amdgcn_mfma_f32_16x16x32_bf16(a1h, bh, acc[1][nt], 0, 0, 0);
                    acc[0][nt] = __builtin_amdgcn_mfma_f32_16x16x32_bf16(a0h, bl, acc[0][nt], 0, 0, 0);
                    acc[1][nt] = __builtin_amdgcn_mfma_f32_16x16x32_bf16(a1h, bl, acc[1][nt], 0, 0, 0);
                    acc[0][nt] = __builtin_amdgcn_mfma_f32_16x16x32_bf16(a0l, bh, acc[0][nt], 0, 0, 0);
                    acc[1][nt] = __builtin_amdgcn_mfma_f32_16x16x32_bf16(a1l, bh, acc[1][nt], 0, 0, 0);
                }
            }
            __syncthreads();
        }
        const int q4 = (lane >> 4) << 2;
        #pragma unroll
        for (int nt = 0; nt < 4; ++nt) {
            int o = o0 + (nt << 4) + lm;
            float bv = cb.dp_bias[o];
            #pragma unroll
            for (int mt = 0; mt < 2; ++mt) {
                #pragma unroll
                for (int rg = 0; rg < 4; ++rg) {
                    int s = s0 + wm + (mt << 4) + q4 + rg;
                    float v = fmaxf(acc[mt][nt][rg] + bv, 0.f);
                    size_t off = ((size_t)b * S_ + s) * D_ + o;
                    if (cb.bfout) {
                        unsigned short hi = f2bf(v);
                        cb.dp_out_hi[off] = hi;
                        cb.dp_out_lo[off] = f2bf(v - bf2f(hi));
                    } else {
                        cb.dp_out_f[off] = v;
                    }
                }
            }
        }
    } else {
        // ---------------- pp/ep plain bf16 path ----------------
        const int z1 = z - 1;
        unsigned short* Asb = (unsigned short*)smem;            // [130][40]
        unsigned short* Bsb = (unsigned short*)(smem + 10400);  // [3][64][40]
        const unsigned short* inb = cb.inb[z1] + (size_t)b * S_ * D_;
        const unsigned short* wtp = cb.wt[z1];
        const float* bias = cb.bias[z1];
        uint4 pa[3], pb[3];
        auto pref = [&](int c0) {
            #pragma unroll
            for (int rr = 0; rr < 3; ++rr) {
                uint4 v = make_uint4(0u, 0u, 0u, 0u);
                if (va[rr])
                    v = *(const uint4*)(const void*)(inb + (size_t)sa[rr] * D_ + c0 + pa_off[rr]);
                pa[rr] = v;
                pb[rr] = *(const uint4*)(const void*)(wtp + ((size_t)kb[rr] * 256 + (o0 + ob[rr])) * 256 + c0 + pbo[rr]);
            }
        };
        pref(0);
        for (int c0 = 0; c0 < D_; c0 += 32) {
            #pragma unroll
            for (int rr = 0; rr < 3; ++rr) {
                if (tid + (rr << 8) < 520)
                    *(uint4*)(void*)&Asb[ta[rr] * 40 + pa_off[rr]] = pa[rr];
                *(uint4*)(void*)&Bsb[((kb[rr] << 6) + ob[rr]) * 40 + pbo[rr]] = pb[rr];
            }
            __syncthreads();
            if (c0 + 32 < D_) pref(c0 + 32);
            #pragma unroll
            for (int k = 0; k < 3; ++k) {
                short8x a0 = *(short8x*)(void*)&Asb[(wm + lm + k) * 40 + lk8];
                short8x a1 = *(short8x*)(void*)&Asb[(wm + 16 + lm + k) * 40 + lk8];
                #pragma unroll
                for (int nt = 0; nt < 4; ++nt) {
                    short8x bf = *(short8x*)(void*)&Bsb[((k << 6) + (nt << 4) + lm) * 40 + lk8];
                    acc[0][nt] = __builtin_amdgcn_mfma_f32_16x16x32_bf16(a0, bf, acc[0][nt], 0, 0, 0);
                    acc[1][nt] = __builtin_amdgcn_mfma_f32_16x16x32_bf16(a1, bf, acc[1][nt], 0, 0, 0);
                }
            }
            __syncthreads();
        }
        // epilogue: C/D layout col=lane&15, row=(lane>>4)*4+reg
        const int q4 = (lane >> 4) << 2;
        #pragma unroll
        for (int nt = 0; nt < 4; ++nt) {
            int o = o0 + (nt << 4) + lm;
            float bv = bias[o];
            #pragma unroll
            for (int mt = 0; mt < 2; ++mt) {
                #pragma unroll
                for (int rg = 0; rg < 4; ++rg) {
                    int s = s0 + wm + (mt << 4) + q4 + rg;
                    float v = fmaxf(acc[mt][nt][rg] + bv, 0.f);
                    size_t off = ((size_t)b * S_ + s) * D_ + o;
                    if (cb.bfout) ((unsigned short*)cb.out[z1])[off] = f2bf(v);
                    else          ((float*)cb.out[z1])[off] = v;
                }
            }
        }
    }
}

// ============================================================
// K5: fused final linears + epilogues. 1 wave = 1 row.
// ============================================================
__global__ __launch_bounds__(256) void linfused_kernel(
    const float* __restrict__ h2dp, const float* __restrict__ h2pp, const float* __restrict__ h2ep,
    const float* __restrict__ dp_wl, const float* __restrict__ dp_bl,
    const float* __restrict__ pp_wl, const float* __restrict__ pp_bl,
    const float* __restrict__ ep_wl, const float* __restrict__ ep_bl,
    const float* __restrict__ nxn, const float* __restrict__ nx, const unsigned* __restrict__ red,
    float* __restrict__ o_logdur, float* __restrict__ o_dur, float* __restrict__ durf,
    float* __restrict__ o_pitch, float* __restrict__ o_energy)
{
    int row = blockIdx.x * 4 + (threadIdx.x >> 6);
    int lane = threadIdx.x & 63;
    float4 hd = ((const float4*)(h2dp + (size_t)row * F_))[lane];
    float4 wd = ((const float4*)dp_wl)[lane];
    float ad = hd.x * wd.x + hd.y * wd.y + hd.z * wd.z + hd.w * wd.w;

    float4 he = ((const float4*)(h2ep + (size_t)row * F_))[lane];
    float4 we = ((const float4*)ep_wl)[lane];
    float ae = he.x * we.x + he.y * we.y + he.z * we.z + he.w * we.w;

    float4 hp = ((const float4*)(h2pp + (size_t)row * F_))[lane];
    float hv[4] = { hp.x, hp.y, hp.z, hp.w };
    float a0 = 0.f, a1 = 0.f, a2 = 0.f;
    #pragma unroll
    for (int u = 0; u < 4; ++u) {
        int c = lane * 4 + u;
        a0 = fmaf(hv[u], pp_wl[c * 3 + 0], a0);
        a1 = fmaf(hv[u], pp_wl[c * 3 + 1], a1);
        a2 = fmaf(hv[u], pp_wl[c * 3 + 2], a2);
    }
    #pragma unroll
    for (int m = 32; m; m >>= 1) {
        ad += __shfl_xor(ad, m);
        ae += __shfl_xor(ae, m);
        a0 += __shfl_xor(a0, m); a1 += __shfl_xor(a1, m); a2 += __shfl_xor(a2, m);
    }
    if (lane == 0) {
        // duration epilogue
        float base = ad + dp_bl[0];
        float es = 0.8f + 0.4f * (nxn[row] / __uint_as_float(red[0]));
        int s = row & (S_ - 1);
        float ps = 1.0f + 0.1f * ((float)s * (1.f / (float)S_));
        float ld = base * es * ps;
        float d = expf(ld);
        o_logdur[row] = ld;
        o_dur[row] = d;
        durf[row] = d;
        // pitch epilogue
        float p0 = a0 + pp_bl[0], p1 = a1 + pp_bl[1], p2 = a2 + pp_bl[2];
        float mn = __uint_as_float(red[1]), mx = __uint_as_float(red[2]);
        float en = (nx[row] - mn) / (mx - mn + 1e-8f);
        float f0s = 100.f + 400.f * en;
        float f0b = expf(p0) * f0s * (1.f / 220.f);
        o_pitch[(size_t)row * 3 + 0] = logf(f0b + 1e-8f);
        o_pitch[(size_t)row * 3 + 1] = p1;
        o_pitch[(size_t)row * 3 + 2] = p2;
        // energy
        o_energy[row] = ae + ep_bl[0];
    }
}

// ============================================================
// K6: per-batch round->cumsum->clip->searchsorted + mel mask
// ============================================================
__global__ __launch_bounds__(1024) void regulate_kernel(
    const float* __restrict__ durf, int* __restrict__ idxbuf, float* __restrict__ mask)
{
    __shared__ int cum[S_];
    int b = blockIdx.x;
    int t = threadIdx.x;
    int d = (int)rintf(durf[b * S_ + t]);
    cum[t] = d;
    __syncthreads();
    for (int off = 1; off < S_; off <<= 1) {
        int v = (t >= off) ? cum[t - off] : 0;
        __syncthreads();
        cum[t] += v;
        __syncthreads();
    }
    cum[t] = min(cum[t], T_);
    __syncthreads();
    int total = cum[S_ - 1];
    for (int t0 = t; t0 < T_; t0 += S_) {
        int lo = 0, hi = S_;
        while (lo < hi) {
            int mid = (lo + hi) >> 1;
            if (cum[mid] <= t0) lo = mid + 1; else hi = mid;
        }
        int id = min(lo, S_ - 1);
        bool masked = (t0 >= total);
        idxbuf[b * T_ + t0] = masked ? -1 : id;
        mask[(size_t)b * T_ + t0] = masked ? 1.f : 0.f;
    }
}

// ============================================================
// K7: expanded gather. 1 wave = 1 (b,t) row, float4/lane
// ============================================================
__global__ __launch_bounds__(256) void expand_kernel(
    const float* __restrict__ xp, const int* __restrict__ idxbuf, float* __restrict__ expd)
{
    int row = blockIdx.x * 4 + (threadIdx.x >> 6);
    int lane = threadIdx.x & 63;
    int id = idxbuf[row];
    int b = row >> 13;
    float4 v = make_float4(0.f, 0.f, 0.f, 0.f);
    if (id >= 0)
        v = ((const float4*)(xp + ((size_t)(b * S_ + id)) * D_))[lane];
    ((float4*)(expd + (size_t)row * D_))[lane] = v;
}

// ============================================================
extern "C" void kernel_launch(void* const* d_in, const int* in_sizes, int n_in,
                              void* d_out, int out_size, void* d_ws, size_t ws_size,
                              hipStream_t stream) {
    const float* x     = (const float*)d_in[0];
    const float* note  = (const float*)d_in[2];
    const float* ln_g  = (const float*)d_in[3];
    const float* ln_b  = (const float*)d_in[4];
    const float* dp_w1 = (const float*)d_in[5];
    const float* dp_b1 = (const float*)d_in[6];
    const float* dp_w2 = (const float*)d_in[7];
    const float* dp_b2 = (const float*)d_in[8];
    const float* dp_wl = (const float*)d_in[9];
    const float* dp_bl = (const float*)d_in[10];
    const float* pp_w1 = (const float*)d_in[11];
    const float* pp_b1 = (const float*)d_in[12];
    const float* pp_w2 = (const float*)d_in[13];
    const float* pp_b2 = (const float*)d_in[14];
    const float* pp_wl = (const float*)d_in[15];
    const float* pp_bl = (const float*)d_in[16];
    const float* ep_w1 = (const float*)d_in[17];
    const float* ep_b1 = (const float*)d_in[18];
    const float* ep_w2 = (const float*)d_in[19];
    const float* ep_b2 = (const float*)d_in[20];
    const float* ep_wl = (const float*)d_in[21];
    const float* ep_bl = (const float*)d_in[22];
    const float* np_w  = (const float*)d_in[23];
    const float* np_b  = (const float*)d_in[24];

    // d_out: logdur | dur | pitch | energy | expanded | melmask
    float* o_logdur = (float*)d_out;
    float* o_dur    = o_logdur + ROWS;
    float* o_pitch  = o_dur + ROWS;
    float* o_energy = o_pitch + ROWS * 3;
    float* o_exp    = o_energy + ROWS;
    float* o_mask   = o_exp + (size_t)B_ * T_ * D_;

    // intermediates inside the expanded region (rewritten last by expand)
    const size_t CH = (size_t)ROWS * D_;      // 4,194,304 floats
    float* h2_dp = o_exp + 0 * CH;
    float* h2_pp = o_exp + 1 * CH;
    float* h2_ep = o_exp + 2 * CH;
    unsigned short* h1_ppb  = (unsigned short*)(o_exp + 3 * CH);            // CH bf16
    unsigned short* h1_epb  = (unsigned short*)(o_exp + 3 * CH + CH / 2);   // CH bf16
    unsigned short* xp_bf   = (unsigned short*)(o_exp + 4 * CH);            // CH bf16
    unsigned short* xn_hi   = (unsigned short*)(o_exp + 4 * CH + CH / 2);   // CH bf16
    unsigned short* xn_lo   = (unsigned short*)(o_exp + 5 * CH);            // CH bf16
    unsigned short* h1dp_hi = (unsigned short*)(o_exp + 5 * CH + CH / 2);   // CH bf16
    unsigned short* h1dp_lo = (unsigned short*)(o_exp + 6 * CH);            // CH bf16
    unsigned short* wt      = (unsigned short*)(o_exp + 6 * CH + CH / 2);   // 8*196608 bf16
    unsigned short* wt_pp1  = wt;
    unsigned short* wt_ep1  = wt + 196608;
    unsigned short* wt_pp2  = wt + 2 * 196608;
    unsigned short* wt_ep2  = wt + 3 * 196608;
    unsigned short* wt_dp1h = wt + 4 * 196608;
    unsigned short* wt_dp1l = wt + 5 * 196608;
    unsigned short* wt_dp2h = wt + 6 * 196608;
    unsigned short* wt_dp2l = wt + 7 * 196608;

    // d_ws: xprime | norm_xn | norm_x | red | durf | idx
    float* ws_f    = (float*)d_ws;
    float* xprime  = ws_f;
    float* norm_xn = ws_f + CH;
    float* norm_x  = norm_xn + ROWS;
    unsigned* red  = (unsigned*)(norm_x + ROWS);
    float* durf    = (float*)(red + 4);
    int*   idxbuf  = (int*)(durf + ROWS);

    wprep_kernel<<<1536, 256, 0, stream>>>(pp_w1, ep_w1, pp_w2, ep_w2, dp_w1, dp_w2, wt);
    noteproj_kernel<<<dim3(ROWS / 64, D_ / 64), 256, 0, stream>>>(x, note, np_w, np_b, xprime, red);
    rowstats_kernel<<<ROWS / 4, 256, 0, stream>>>(xprime, ln_g, ln_b, xn_hi, xn_lo, norm_xn, norm_x, xp_bf);
    reduce_fast_kernel<<<32, 256, 0, stream>>>(norm_xn, norm_x, red);

    dim3 cgrid(B_ * (S_ / 128), F_ / 64, 3);
    ConvAll s1;
    s1.dp_in_hi = xn_hi;   s1.dp_in_lo = xn_lo;
    s1.dp_wt_hi = wt_dp1h; s1.dp_wt_lo = wt_dp1l;
    s1.dp_bias = dp_b1;
    s1.dp_out_hi = h1dp_hi; s1.dp_out_lo = h1dp_lo; s1.dp_out_f = nullptr;
    s1.inb[0] = xp_bf;  s1.wt[0] = wt_pp1; s1.bias[0] = pp_b1; s1.out[0] = (void*)h1_ppb;
    s1.inb[1] = xp_bf;  s1.wt[1] = wt_ep1; s1.bias[1] = ep_b1; s1.out[1] = (void*)h1_epb;
    s1.bfout = 1;
    convall_kernel<<<cgrid, 256, 0, stream>>>(s1);

    ConvAll s2;
    s2.dp_in_hi = h1dp_hi; s2.dp_in_lo = h1dp_lo;
    s2.dp_wt_hi = wt_dp2h; s2.dp_wt_lo = wt_dp2l;
    s2.dp_bias = dp_b2;
    s2.dp_out_hi = nullptr; s2.dp_out_lo = nullptr; s2.dp_out_f = h2_dp;
    s2.inb[0] = h1_ppb; s2.wt[0] = wt_pp2; s2.bias[0] = pp_b2; s2.out[0] = (void*)h2_pp;
    s2.inb[1] = h1_epb; s2.wt[1] = wt_ep2; s2.bias[1] = ep_b2; s2.out[1] = (void*)h2_ep;
    s2.bfout = 0;
    convall_kernel<<<cgrid, 256, 0, stream>>>(s2);

    linfused_kernel<<<ROWS / 4, 256, 0, stream>>>(h2_dp, h2_pp, h2_ep,
        dp_wl, dp_bl, pp_wl, pp_bl, ep_wl, ep_bl,
        norm_xn, norm_x, red, o_logdur, o_dur, durf, o_pitch, o_energy);

    regulate_kernel<<<B_, 1024, 0, stream>>>(durf, idxbuf, o_mask);
    expand_kernel<<<(B_ * T_) / 4, 256, 0, stream>>>(xprime, idxbuf, o_exp);
}